// Round 5
// baseline (117.785 us; speedup 1.0000x reference)
//
#include <hip/hip_runtime.h>

// ---------------------------------------------------------------------------
// 9-qubit batched state-vector simulator, v5.
//  - TWO batch elements per wave (ILP): element 1 staged at LDS +512 (free
//    4096-B immediate ds offset on shared address registers); diag/phase
//    table loads and all addressing shared between the two elements.
//  - Gates forced to packed fp32 via inline asm v_pk_mul/fma_f32; the gate
//    table stores duplicated {c,c},{s,s},{-s,-s} so no VOP3P modifiers are
//    needed (coefficients come in as uniform SGPR pairs).
//  - Batch-independent tables built by a one-block pre-kernel into d_ws.
//  - Per-wave LDS staging, sigma(i)=i^(i>>4) swizzle, no __syncthreads.
// ---------------------------------------------------------------------------

typedef float v2f __attribute__((ext_vector_type(2)));

constexpr int pf(int l, int i) {        // forward CNOT-ring basis map, layer l
    const int r = l + 1; int j = i;
    for (int c = 0; c < 9; ++c) {
        const int bit = (j >> (8 - c)) & 1;
        const int t = (c + r) % 9;
        j ^= bit << (8 - t);
    }
    return j;
}
constexpr int sg(int i) { return i ^ (i >> 4); }   // LDS anti-conflict swizzle

// bit p of P_bd(j) = parity(j & PM.m[bd][p])
struct PMask { int m[2][9]; };
constexpr PMask make_pmask() {
    PMask pm{};
    for (int bd = 0; bd < 2; ++bd)
        for (int q = 0; q < 9; ++q) {
            const int img = pf(bd, 1 << q);
            for (int p = 0; p < 9; ++p)
                if ((img >> p) & 1) pm.m[bd][p] |= 1 << q;
        }
    return pm;
}
constexpr PMask PM = make_pmask();

struct T3Tab { int laneBase[2][6]; int regPart[2][8]; };
constexpr T3Tab make_t3() {
    T3Tab t{};
    for (int l = 0; l < 2; ++l) {
        for (int b = 0; b < 6; ++b) t.laneBase[l][b] = sg(pf(l, 1 << b));
        for (int g = 0; g < 8; ++g) t.regPart [l][g] = sg(pf(l, g << 6));
    }
    return t;
}
constexpr T3Tab T3T = make_t3();

constexpr int sgk3(int k) { return (k << 3) ^ (k >> 1); }   // sg(k<<3)
constexpr int sgk6(int k) { return (k << 6) ^ (k << 2); }   // sg(k<<6)

#define PI_F 3.14159265358979323846f

// ws layout (floats):
//   [0..216)        gates: 27 x 8 floats {c,c,s,s,-s,-s,0,0}
//   [216..1240)     diag0 (512 v2f)   merged boundary phase, layers 1->2
//   [1240..2264)    diag1 (512 v2f)   merged boundary phase, layers 2->3
//   [2264..3288)    PH    (512 v2f)   init-state phase
__global__ __launch_bounds__(512) void qtab_kernel(
        const float* __restrict__ wt, float* __restrict__ ws) {
    const int j = threadIdx.x;             // 0..511
    if (j < 27) {
        float s, c; __sincosf(0.5f * wt[j * 3 + 1], &s, &c);
        float* g = ws + j * 8;
        g[0] = c;  g[1] = c;  g[2] = s;  g[3] = s;
        g[4] = -s; g[5] = -s; g[6] = 0.f; g[7] = 0.f;
    }
    v2f* dv = (v2f*)(ws + 216);
    #pragma unroll
    for (int bd = 0; bd < 2; ++bd) {
        float alpha = 0.0f;
        #pragma unroll
        for (int p = 0; p < 9; ++p) {
            const int w = 8 - p;
            const float om = wt[(bd * 9 + w) * 3 + 2];        // omega, layer bd
            const float ph = wt[((bd + 1) * 9 + w) * 3 + 0];  // phi, layer bd+1
            alpha += ((j >> p) & 1) ? 0.5f * om : -0.5f * om;
            alpha += (__popc(j & PM.m[bd][p]) & 1) ? 0.5f * ph : -0.5f * ph;
        }
        float sn, cs; __sincosf(alpha, &sn, &cs);
        dv[bd * 512 + j] = (v2f){cs, sn};
    }
    {
        float a = 0.0f;
        #pragma unroll
        for (int p = 0; p < 9; ++p) {
            const int w = 8 - p;
            const float phi = wt[w * 3 + 0];
            a += ((j >> p) & 1) ? (0.5f * phi - 0.5f * PI_F) : (-0.5f * phi);
        }
        float sn, cs; __sincosf(a, &sn, &cs);
        dv[1024 + j] = (v2f){cs, sn};
    }
}

// packed real-Y gate on both elements (a[0..7] el0, a[8..15] el1):
//   n0 = a0*c + a1*(-s) ; n1 = a0*s + a1*c   (re & im packed)
#define APPLY_GATE(gidx, KB)                                                  \
    {                                                                         \
        const float* gp = GT + (gidx) * 8;                                    \
        const v2f cc = *(const v2f*)(gp + 0);                                 \
        const v2f ss = *(const v2f*)(gp + 2);                                 \
        const v2f ns = *(const v2f*)(gp + 4);                                 \
        _Pragma("unroll")                                                     \
        for (int e = 0; e < 16; e += 8) {                                     \
            _Pragma("unroll")                                                 \
            for (int k0 = 0; k0 < 8; ++k0) if (!(k0 & (KB))) {                \
                const int i0 = e + k0, i1 = e + (k0 | (KB));                  \
                v2f t0, t1, n0, n1;                                           \
                asm("v_pk_mul_f32 %0, %1, %2"                                 \
                    : "=v"(t0) : "v"(a[i1]), "s"(ns));                        \
                asm("v_pk_mul_f32 %0, %1, %2"                                 \
                    : "=v"(t1) : "v"(a[i1]), "s"(cc));                        \
                asm("v_pk_fma_f32 %0, %1, %2, %3"                             \
                    : "=v"(n0) : "v"(a[i0]), "s"(cc), "v"(t0));               \
                asm("v_pk_fma_f32 %0, %1, %2, %3"                             \
                    : "=v"(n1) : "v"(a[i0]), "s"(ss), "v"(t1));               \
                a[i0] = n0; a[i1] = n1;                                       \
            }                                                                 \
        }                                                                     \
    }

__global__ __launch_bounds__(256, 5) void qsim_kernel(
        const float* __restrict__ x,       // (batch, 9)
        const float* __restrict__ tab,     // ws tables
        float* __restrict__ out,           // (batch, 9)
        int batch) {
    __shared__ v2f st[4][1024];            // per-wave staging, 2 elems (32 KiB)

    const int tid  = threadIdx.x;
    const int wv   = tid >> 6;
    const int lane = tid & 63;
    const int b0   = (blockIdx.x * 4 + wv) * 2;   // two consecutive elements
    if (b0 >= batch) return;

    v2f* __restrict__ S = st[wv];
    const float* __restrict__ GT = tab;
    const v2f* __restrict__ D0 = (const v2f*)(tab + 216);
    const v2f* __restrict__ D1 = D0 + 512;
    const v2f* __restrict__ PH = D0 + 1024;

    // ---- init both elements: magnitudes from x, phase from table ----
    v2f a[16];
    #pragma unroll
    for (int e = 0; e < 2; ++e) {
        const int b = b0 + e;
        float cx[9], sx[9];
        #pragma unroll
        for (int w = 0; w < 9; ++w)
            __sincosf(0.5f * x[b * 9 + w], &sx[w], &cx[w]);
        float P = 1.0f;
        #pragma unroll
        for (int w = 0; w < 6; ++w)
            P *= ((lane >> (5 - w)) & 1) ? sx[w] : cx[w];
        #pragma unroll
        for (int k = 0; k < 8; ++k) {
            const float m = P * ((k & 4) ? sx[6] : cx[6])
                              * ((k & 2) ? sx[7] : cx[7])
                              * ((k & 1) ? sx[8] : cx[8]);
            a[e * 8 + k] = PH[(lane << 3) | k] * m;
        }
    }

    // ---- swizzled address bases (shared by both elements) ----
    const int baseA = (lane << 3) ^ (lane >> 1);            // sg(L<<3)
    const int hB    = ((lane & 0x38) << 3) | (lane & 7);
    const int baseB = hB ^ (hB >> 4);
    const int baseC = lane ^ (lane >> 4);
    int t3b[2];
    #pragma unroll
    for (int l = 0; l < 2; ++l) {
        int v = 0;
        #pragma unroll
        for (int bb = 0; bb < 6; ++bb)
            v ^= ((lane >> bb) & 1) ? T3T.laneBase[l][bb] : 0;
        t3b[l] = v;
    }

    // ---- 3 layers of 9 packed real-Ry gates, swizzled LDS layout cycling ----
    #pragma unroll
    for (int l = 0; l < 3; ++l) {
        APPLY_GATE(l * 9 + 6, 4);   // layout A: reg bits = qubits 6,7,8
        APPLY_GATE(l * 9 + 7, 2);
        APPLY_GATE(l * 9 + 8, 1);

        #pragma unroll
        for (int k = 0; k < 8; ++k) {
            const int ad = baseA ^ k;
            S[ad] = a[k]; S[ad + 512] = a[8 + k];
        }
        #pragma unroll
        for (int k = 0; k < 8; ++k) {
            const int ad = baseB ^ sgk3(k);
            a[k] = S[ad]; a[8 + k] = S[ad + 512];
        }

        APPLY_GATE(l * 9 + 3, 4);   // layout B: reg bits = qubits 3,4,5
        APPLY_GATE(l * 9 + 4, 2);
        APPLY_GATE(l * 9 + 5, 1);

        #pragma unroll
        for (int k = 0; k < 8; ++k) {
            const int ad = baseB ^ sgk3(k);
            S[ad] = a[k]; S[ad + 512] = a[8 + k];
        }
        #pragma unroll
        for (int k = 0; k < 8; ++k) {
            const int ad = baseC ^ sgk6(k);
            a[k] = S[ad]; a[8 + k] = S[ad + 512];
        }

        APPLY_GATE(l * 9 + 0, 4);   // layout C: reg bits = qubits 0,1,2
        APPLY_GATE(l * 9 + 1, 2);
        APPLY_GATE(l * 9 + 2, 1);

        if (l < 2) {
            // merged boundary diagonal (basis j = k<<6 | lane), shared load
            const v2f* __restrict__ D = (l == 0) ? D0 : D1;
            #pragma unroll
            for (int k = 0; k < 8; ++k) {
                const v2f d = D[(k << 6) | lane];
                const v2f u = a[k];
                a[k]     = (v2f){u.x * d.x - u.y * d.y, u.x * d.y + u.y * d.x};
                const v2f w2 = a[8 + k];
                a[8 + k] = (v2f){w2.x * d.x - w2.y * d.y, w2.x * d.y + w2.y * d.x};
            }
            // T3: C -> A with the CNOT-ring permutation folded in
            #pragma unroll
            for (int k = 0; k < 8; ++k) {
                const int ad = t3b[l] ^ T3T.regPart[l][k];
                S[ad] = a[k]; S[ad + 512] = a[8 + k];
            }
            #pragma unroll
            for (int k = 0; k < 8; ++k) {
                const int ad = baseA ^ k;
                a[k] = S[ad]; a[8 + k] = S[ad + 512];
            }
        }
    }

    // ---- epilogue: both elements, P_3 folded into sign masks ----
    float p0[8], p1[8];
    #pragma unroll
    for (int k = 0; k < 8; ++k) {
        const v2f q0 = a[k] * a[k];         p0[k] = q0.x + q0.y;
        const v2f q1 = a[8 + k] * a[8 + k]; p1[k] = q1.x + q1.y;
    }

    v2f Sv = (v2f){0.f, 0.f}, U4 = Sv, U2 = Sv, U1 = Sv;
    #pragma unroll
    for (int k = 0; k < 8; ++k) {
        const v2f q = (v2f){p0[k], p1[k]};
        Sv += q;
        U4 += (k & 4) ? -q : q;
        U2 += (k & 2) ? -q : q;
        U1 += (k & 1) ? -q : q;
    }

    const bool l25 = ((lane >> 2) ^ (lane >> 5)) & 1;
    const bool l14 = ((lane >> 1) ^ (lane >> 4)) & 1;
    const bool l03 = ( lane       ^ (lane >> 3)) & 1;
    const bool l5  = (lane >> 5) & 1;
    const bool l4  = (lane >> 4) & 1;
    const bool l3  = (lane >> 3) & 1;

    v2f c[9];
    c[0] = l25 ? -Sv : Sv;
    c[1] = l14 ? -Sv : Sv;
    c[2] = l03 ? -Sv : Sv;
    c[3] = l5  ? -U4 : U4;
    c[4] = l4  ? -U2 : U2;
    c[5] = l3  ? -U1 : U1;
    c[6] = l25 ? -U4 : U4;
    c[7] = l14 ? -U2 : U2;
    c[8] = l03 ? -U1 : U1;

    #pragma unroll
    for (int d = 1; d < 64; d <<= 1) {
        #pragma unroll
        for (int w = 0; w < 9; ++w) {
            v2f o;
            o.x = __shfl_xor(c[w].x, d, 64);
            o.y = __shfl_xor(c[w].y, d, 64);
            c[w] += o;
        }
    }

    // lanes 0..8 -> element b0 outputs, lanes 9..17 -> element b0+1
    float v = c[0].x;
    #pragma unroll
    for (int w = 1; w < 9; ++w)
        v = (lane == w) ? c[w].x : v;
    #pragma unroll
    for (int w = 0; w < 9; ++w)
        v = (lane == w + 9) ? c[w].y : v;
    if (lane < 18)
        out[b0 * 9 + lane] = v;     // contiguous 18-float store
}

extern "C" void kernel_launch(void* const* d_in, const int* in_sizes, int n_in,
                              void* d_out, int out_size, void* d_ws, size_t ws_size,
                              hipStream_t stream) {
    const float* x  = (const float*)d_in[0];   // (32768, 9) fp32
    const float* wt = (const float*)d_in[1];   // (3, 9, 3) fp32
    float* out = (float*)d_out;                // (32768, 9) fp32
    const int batch = in_sizes[0] / 9;
    float* ws = (float*)d_ws;                  // 3288 floats = 12.9 KB used

    hipLaunchKernelGGL(qtab_kernel, dim3(1), dim3(512), 0, stream, wt, ws);
    hipLaunchKernelGGL(qsim_kernel, dim3((batch + 7) / 8), dim3(256), 0, stream,
                       x, ws, out, batch);
}

// Round 6
// 112.556 us; speedup vs baseline: 1.0465x; 1.0465x over previous
//
#include <hip/hip_runtime.h>

// ---------------------------------------------------------------------------
// 9-qubit batched state-vector simulator, v6.
//  - one batch element per wave (32 waves/CU, 16 KB LDS/block) — v5's
//    2-elem ILP regressed: fewer resident waves couldn't hide the doubled
//    serial DS round-trip. TLP wins here.
//  - gates as packed fp32 (inline asm v_pk_mul/fma_f32, coeffs from SGPRs)
//  - boundary diagonal cmul packed via op_sel-swapped v_pk_fma (2 instr),
//    table stored as {dx,dx,-dy,dy} float4 (one coalesced b128 load)
//  - init trig via raw v_sin/v_cos (revolutions) — 2 instr per angle
//  - epilogue via fast Walsh-Hadamard butterfly (24 shfl vs 108)
//  - batch-independent tables built once by a one-block pre-kernel in d_ws
// ---------------------------------------------------------------------------

typedef float v2f __attribute__((ext_vector_type(2)));

constexpr int pf(int l, int i) {        // forward CNOT-ring basis map, layer l
    const int r = l + 1; int j = i;
    for (int c = 0; c < 9; ++c) {
        const int bit = (j >> (8 - c)) & 1;
        const int t = (c + r) % 9;
        j ^= bit << (8 - t);
    }
    return j;
}
constexpr int sg(int i) { return i ^ (i >> 4); }   // LDS anti-conflict swizzle

struct PMask { int m[2][9]; };
constexpr PMask make_pmask() {
    PMask pm{};
    for (int bd = 0; bd < 2; ++bd)
        for (int q = 0; q < 9; ++q) {
            const int img = pf(bd, 1 << q);
            for (int p = 0; p < 9; ++p)
                if ((img >> p) & 1) pm.m[bd][p] |= 1 << q;
        }
    return pm;
}
constexpr PMask PM = make_pmask();

struct T3Tab { int laneBase[2][6]; int regPart[2][8]; };
constexpr T3Tab make_t3() {
    T3Tab t{};
    for (int l = 0; l < 2; ++l) {
        for (int b = 0; b < 6; ++b) t.laneBase[l][b] = sg(pf(l, 1 << b));
        for (int g = 0; g < 8; ++g) t.regPart [l][g] = sg(pf(l, g << 6));
    }
    return t;
}
constexpr T3Tab T3T = make_t3();

constexpr int sgk3(int k) { return (k << 3) ^ (k >> 1); }   // sg(k<<3)
constexpr int sgk6(int k) { return (k << 6) ^ (k << 2); }   // sg(k<<6)

#define PI_F    3.14159265358979323846f
#define INV2PI  0.15915494309189535f

// ws layout (floats):
//   [0..216)          gates: 27 x 8 floats {c,c,s,s,-s,-s,0,0}
//   [216..2264)       D0q: 512 float4 {dx,dx,-dy,dy}  boundary 1->2
//   [2264..4312)      D1q: 512 float4                 boundary 2->3
//   [4312..5336)      PH : 512 v2f init-state phase
__global__ __launch_bounds__(512) void qtab_kernel(
        const float* __restrict__ wt, float* __restrict__ ws) {
    const int j = threadIdx.x;             // 0..511
    if (j < 27) {
        float s, c; __sincosf(0.5f * wt[j * 3 + 1], &s, &c);
        float* g = ws + j * 8;
        g[0] = c;  g[1] = c;  g[2] = s;  g[3] = s;
        g[4] = -s; g[5] = -s; g[6] = 0.f; g[7] = 0.f;
    }
    float4* dq = (float4*)(ws + 216);
    #pragma unroll
    for (int bd = 0; bd < 2; ++bd) {
        float alpha = 0.0f;
        #pragma unroll
        for (int p = 0; p < 9; ++p) {
            const int w = 8 - p;
            const float om = wt[(bd * 9 + w) * 3 + 2];        // omega, layer bd
            const float ph = wt[((bd + 1) * 9 + w) * 3 + 0];  // phi, layer bd+1
            alpha += ((j >> p) & 1) ? 0.5f * om : -0.5f * om;
            alpha += (__popc(j & PM.m[bd][p]) & 1) ? 0.5f * ph : -0.5f * ph;
        }
        float sn, cs; __sincosf(alpha, &sn, &cs);
        dq[bd * 512 + j] = make_float4(cs, cs, -sn, sn);
    }
    {
        float a = 0.0f;
        #pragma unroll
        for (int p = 0; p < 9; ++p) {
            const int w = 8 - p;
            const float phi = wt[w * 3 + 0];
            a += ((j >> p) & 1) ? (0.5f * phi - 0.5f * PI_F) : (-0.5f * phi);
        }
        float sn, cs; __sincosf(a, &sn, &cs);
        ((v2f*)(ws + 4312))[j] = (v2f){cs, sn};
    }
}

// packed real-Y gate: n0 = c*a0 - s*a1 ; n1 = s*a0 + c*a1  (re & im packed)
#define APPLY_GATE(gidx, KB)                                                  \
    {                                                                         \
        const float* gp = GT + (gidx) * 8;                                    \
        const v2f cc = *(const v2f*)(gp + 0);                                 \
        const v2f ss = *(const v2f*)(gp + 2);                                 \
        const v2f ns = *(const v2f*)(gp + 4);                                 \
        _Pragma("unroll")                                                     \
        for (int k0 = 0; k0 < 8; ++k0) if (!(k0 & (KB))) {                    \
            const int k1 = k0 | (KB);                                         \
            v2f t0, t1, n0, n1;                                               \
            asm("v_pk_mul_f32 %0, %1, %2" : "=v"(t0) : "v"(a[k1]), "s"(ns));  \
            asm("v_pk_mul_f32 %0, %1, %2" : "=v"(t1) : "v"(a[k1]), "s"(cc));  \
            asm("v_pk_fma_f32 %0, %1, %2, %3"                                 \
                : "=v"(n0) : "v"(a[k0]), "s"(cc), "v"(t0));                   \
            asm("v_pk_fma_f32 %0, %1, %2, %3"                                 \
                : "=v"(n1) : "v"(a[k0]), "s"(ss), "v"(t1));                   \
            a[k0] = n0; a[k1] = n1;                                           \
        }                                                                     \
    }

__global__ __launch_bounds__(256) void qsim_kernel(
        const float* __restrict__ x,       // (batch, 9)
        const float* __restrict__ tab,     // ws tables
        float* __restrict__ out,           // (batch, 9)
        int batch) {
    __shared__ v2f st[4][512];             // per-wave staging (16 KiB)

    const int tid  = threadIdx.x;
    const int wv   = tid >> 6;
    const int lane = tid & 63;
    const int b    = blockIdx.x * 4 + wv;
    if (b >= batch) return;
    const int bu   = __builtin_amdgcn_readfirstlane(b);   // wave-uniform

    v2f* __restrict__ S = st[wv];
    const float* __restrict__ GT = tab;
    const float4* __restrict__ D0 = (const float4*)(tab + 216);
    const float4* __restrict__ D1 = D0 + 512;
    const v2f*   __restrict__ PH = (const v2f*)(tab + 4312);

    // ---- init: magnitudes via HW trig (revolutions), phase from table ----
    float cx[9], sx[9];
    #pragma unroll
    for (int w = 0; w < 9; ++w) {
        const float rev = x[bu * 9 + w] * (0.5f * INV2PI);
        sx[w] = __builtin_amdgcn_sinf(rev);
        cx[w] = __builtin_amdgcn_cosf(rev);
    }
    float P = 1.0f;
    #pragma unroll
    for (int w = 0; w < 6; ++w)
        P *= ((lane >> (5 - w)) & 1) ? sx[w] : cx[w];

    v2f a[8];
    #pragma unroll
    for (int k = 0; k < 8; ++k) {
        const float m = P * ((k & 4) ? sx[6] : cx[6])
                          * ((k & 2) ? sx[7] : cx[7])
                          * ((k & 1) ? sx[8] : cx[8]);
        a[k] = PH[(lane << 3) | k] * m;
    }

    // ---- swizzled address bases ----
    const int baseA = (lane << 3) ^ (lane >> 1);            // sg(L<<3)
    const int hB    = ((lane & 0x38) << 3) | (lane & 7);
    const int baseB = hB ^ (hB >> 4);
    const int baseC = lane ^ (lane >> 4);
    int t3b[2];
    #pragma unroll
    for (int l = 0; l < 2; ++l) {
        int v = 0;
        #pragma unroll
        for (int bb = 0; bb < 6; ++bb)
            v ^= ((lane >> bb) & 1) ? T3T.laneBase[l][bb] : 0;
        t3b[l] = v;
    }

    // ---- 3 layers of 9 packed real-Ry gates, swizzled LDS layout cycling ----
    #pragma unroll
    for (int l = 0; l < 3; ++l) {
        APPLY_GATE(l * 9 + 6, 4);   // layout A: reg bits = qubits 6,7,8
        APPLY_GATE(l * 9 + 7, 2);
        APPLY_GATE(l * 9 + 8, 1);

        #pragma unroll
        for (int k = 0; k < 8; ++k) S[baseA ^ k] = a[k];
        #pragma unroll
        for (int k = 0; k < 8; ++k) a[k] = S[baseB ^ sgk3(k)];

        APPLY_GATE(l * 9 + 3, 4);   // layout B: reg bits = qubits 3,4,5
        APPLY_GATE(l * 9 + 4, 2);
        APPLY_GATE(l * 9 + 5, 1);

        #pragma unroll
        for (int k = 0; k < 8; ++k) S[baseB ^ sgk3(k)] = a[k];
        #pragma unroll
        for (int k = 0; k < 8; ++k) a[k] = S[baseC ^ sgk6(k)];

        APPLY_GATE(l * 9 + 0, 4);   // layout C: reg bits = qubits 0,1,2
        APPLY_GATE(l * 9 + 1, 2);
        APPLY_GATE(l * 9 + 2, 1);

        if (l < 2) {
            // packed boundary diagonal: a' = u*{dx,dx} + swap(u)*{-dy,dy}
            const float4* __restrict__ D = (l == 0) ? D0 : D1;
            #pragma unroll
            for (int k = 0; k < 8; ++k) {
                const float4 d = D[(k << 6) | lane];
                const v2f dd = (v2f){d.x, d.y};   // {dx,dx}
                const v2f dn = (v2f){d.z, d.w};   // {-dy,dy}
                v2f t, r;
                asm("v_pk_mul_f32 %0, %1, %2" : "=v"(t) : "v"(a[k]), "v"(dd));
                asm("v_pk_fma_f32 %0, %1, %2, %3 op_sel:[1,0,0] op_sel_hi:[0,1,1]"
                    : "=v"(r) : "v"(a[k]), "v"(dn), "v"(t));
                a[k] = r;
            }
            // T3: C -> A with the CNOT-ring permutation folded in
            #pragma unroll
            for (int k = 0; k < 8; ++k)
                S[t3b[l] ^ T3T.regPart[l][k]] = a[k];
            #pragma unroll
            for (int k = 0; k < 8; ++k) a[k] = S[baseA ^ k];
        }
    }

    // ---- epilogue: fast Walsh-Hadamard over lanes ----
    float p[8];
    #pragma unroll
    for (int k = 0; k < 8; ++k) {
        const v2f q = a[k] * a[k];
        p[k] = q.x + q.y;
    }
    float F[4] = {0.f, 0.f, 0.f, 0.f};     // S, U4, U2, U1
    #pragma unroll
    for (int k = 0; k < 8; ++k) {
        F[0] += p[k];
        F[1] += (k & 4) ? -p[k] : p[k];
        F[2] += (k & 2) ? -p[k] : p[k];
        F[3] += (k & 1) ? -p[k] : p[k];
    }
    // 6-step FWHT butterfly: lane m ends with Sum_j (-1)^popc(j&m) F(j)
    #pragma unroll
    for (int d = 1; d < 64; d <<= 1) {
        const float sgn = (lane & d) ? -1.0f : 1.0f;
        #pragma unroll
        for (int w = 0; w < 4; ++w) {
            const float t = __shfl_xor(F[w], d, 64);
            F[w] = fmaf(sgn, F[w], t);
        }
    }
    // gather the 9 needed Walsh coefficients via LDS
    // c0=F_S(36) c1=F_S(18) c2=F_S(9) c3=F_U4(32) c4=F_U2(16) c5=F_U1(8)
    // c6=F_U4(36) c7=F_U2(18) c8=F_U1(9)
    S[lane]      = (v2f){F[0], F[1]};      // float idx: 2m -> F_S, 2m+1 -> F_U4
    S[64 + lane] = (v2f){F[2], F[3]};      // 128+2m -> F_U2, 128+2m+1 -> F_U1
    if (lane < 9) {
        const float* Sf = (const float*)S;
        const int idx = (lane == 0) ? 72  : (lane == 1) ? 36  : (lane == 2) ? 18
                      : (lane == 3) ? 65  : (lane == 4) ? 160 : (lane == 5) ? 145
                      : (lane == 6) ? 73  : (lane == 7) ? 164 : 147;
        out[bu * 9 + lane] = Sf[idx];
    }
}

extern "C" void kernel_launch(void* const* d_in, const int* in_sizes, int n_in,
                              void* d_out, int out_size, void* d_ws, size_t ws_size,
                              hipStream_t stream) {
    const float* x  = (const float*)d_in[0];   // (32768, 9) fp32
    const float* wt = (const float*)d_in[1];   // (3, 9, 3) fp32
    float* out = (float*)d_out;                // (32768, 9) fp32
    const int batch = in_sizes[0] / 9;
    float* ws = (float*)d_ws;                  // 5336 floats = 21.3 KB used

    hipLaunchKernelGGL(qtab_kernel, dim3(1), dim3(512), 0, stream, wt, ws);
    hipLaunchKernelGGL(qsim_kernel, dim3((batch + 3) / 4), dim3(256), 0, stream,
                       x, ws, out, batch);
}